// Round 1
// baseline (951.636 us; speedup 1.0000x reference)
//
#include <hip/hip_runtime.h>
#include <math.h>

#define BATCH 2
#define CCH 64      // C
#define HL 128
#define WL 128
#define HH 256
#define WH 256
#define CFCH 256
#define CIN 72

// workspace layout (float offsets)
constexpr long WS_AL   = 0;                   // a_l   (B*C = 128)
constexpr long WS_BL   = 128;                 // bb_l
constexpr long WS_AH   = 256;                 // a_h
constexpr long WS_BH   = 384;                 // bb_h
constexpr long WS_CNL  = 512;                 // 2*128*128 = 32768
constexpr long WS_CNH  = WS_CNL + 32768;      // 2*256*256 = 131072
constexpr long WS_OFFL = WS_CNH + 131072;     // 2*32*128*128 = 1048576
constexpr long WS_DSL  = WS_OFFL + 1048576;
constexpr long WS_OFFH = WS_DSL + 1048576;    // 2*8*256*256 = 1048576
constexpr long WS_DSH  = WS_OFFH + 1048576;
constexpr long WS_OFFS = WS_DSH + 1048576;    // 2*32*128*128 = 1048576

// ---------------- K1: GroupNorm stats -> per-channel affine coeffs ----------
__global__ void k_stats(const float* __restrict__ xl, const float* __restrict__ xh,
                        const float* __restrict__ gwl, const float* __restrict__ gbl,
                        const float* __restrict__ gwh, const float* __restrict__ gbh,
                        float* __restrict__ ws) {
  int blk = blockIdx.x;          // 0..31
  bool high = blk >= 16;
  int id = blk & 15;
  int b = id >> 3, g = id & 7;   // 8 groups of 8 channels
  const float* x = high ? xh : xl;
  int HW = high ? HH * WH : HL * WL;
  long base = ((long)(b * CCH + g * 8)) * HW;
  long n = (long)8 * HW;
  float s = 0.f, s2 = 0.f;
  for (long i = threadIdx.x; i < n; i += blockDim.x) {
    float v = x[base + i];
    s += v; s2 += v * v;
  }
  __shared__ float sh1[256], sh2[256];
  sh1[threadIdx.x] = s; sh2[threadIdx.x] = s2;
  __syncthreads();
  for (int off = 128; off > 0; off >>= 1) {
    if (threadIdx.x < off) {
      sh1[threadIdx.x] += sh1[threadIdx.x + off];
      sh2[threadIdx.x] += sh2[threadIdx.x + off];
    }
    __syncthreads();
  }
  if (threadIdx.x < 8) {
    float mean = sh1[0] / (float)n;
    float var  = sh2[0] / (float)n - mean * mean;
    float inv  = rsqrtf(var + 1e-5f);
    int c = g * 8 + threadIdx.x;
    const float* gw = high ? gwh : gwl;
    const float* gb = high ? gbh : gbl;
    float a  = gw[c] * inv;
    float bb = gb[c] - mean * a;
    float* abase = ws + (high ? WS_AH : WS_AL);
    abase[b * CCH + c] = a;
    abase[128 + b * CCH + c] = bb;   // bb block sits right after a block
  }
}

// ---------------- K2: per-pixel channel norms ------------------------------
__global__ void k_cn(const float* __restrict__ xl, const float* __restrict__ xh,
                     float* __restrict__ ws) {
  int idx = blockIdx.x * blockDim.x + threadIdx.x;
  const int nlow = BATCH * HL * WL;          // 32768
  const int ntot = nlow + BATCH * HH * WH;   // 163840
  if (idx >= ntot) return;
  if (idx < nlow) {
    int p = idx;
    int b = p / (HL * WL);
    int yx = p % (HL * WL);
    const float* a  = ws + WS_AL;
    const float* bb = ws + WS_BL;
    float s = 0.f;
    for (int c = 0; c < CCH; c++) {
      float v = a[b * CCH + c] * xl[((long)(b * CCH + c)) * (HL * WL) + yx] + bb[b * CCH + c];
      s += v * v;
    }
    ws[WS_CNL + p] = sqrtf(s);
  } else {
    int p = idx - nlow;
    int b = p / (HH * WH);
    int yx = p % (HH * WH);
    const float* a  = ws + WS_AH;
    const float* bb = ws + WS_BH;
    float s = 0.f;
    for (int c = 0; c < CCH; c++) {
      float v = a[b * CCH + c] * xh[((long)(b * CCH + c)) * (HH * WH) + yx] + bb[b * CCH + c];
      s += v * v;
    }
    ws[WS_CNH + p] = sqrtf(s);
  }
}

// ---------------- K3/K4: fused sim + conv1x1_bn heads ----------------------
// NOUT = 64 (low: 32 off + 32 ds) or 16 (high: 8 off + 8 ds)
template<int HSZ, int WSZ, int NOUT>
__global__ void k_head(const float* __restrict__ x,
                       const float* __restrict__ w_off, const float* __restrict__ w_ds,
                       const float* __restrict__ s_off, const float* __restrict__ b_off,
                       const float* __restrict__ s_ds,  const float* __restrict__ b_ds,
                       const float* __restrict__ acoef, const float* __restrict__ bcoef,
                       const float* __restrict__ cn,
                       float* __restrict__ out_off, float* __restrict__ out_ds) {
  __shared__ float wsm[NOUT * CIN];
  const int half = NOUT / 2;
  for (int i = threadIdx.x; i < NOUT * CIN; i += blockDim.x) {
    int o = i / CIN, c = i % CIN;
    wsm[i] = (o < half) ? w_off[o * CIN + c] : w_ds[(o - half) * CIN + c];
  }
  __syncthreads();
  int idx = blockIdx.x * blockDim.x + threadIdx.x;
  int xq = idx % WSZ;
  int yq = (idx / WSZ) % HSZ;
  int b  = idx / (WSZ * HSZ);
  float acc[NOUT];
  #pragma unroll
  for (int o = 0; o < NOUT; o++) acc[o] = 0.f;
  float dot[8];
  #pragma unroll
  for (int j = 0; j < 8; j++) dot[j] = 0.f;
  const int dyv[8] = {-2,-2,-2, 0, 0, 2, 2, 2};
  const int dxv[8] = {-2, 0, 2,-2, 2,-2, 0, 2};
  for (int c = 0; c < CCH; c++) {
    const float* plane = x + ((long)(b * CCH + c)) * (HSZ * WSZ);
    float ac = acoef[b * CCH + c], bc = bcoef[b * CCH + c];
    float xc = ac * plane[yq * WSZ + xq] + bc;
    #pragma unroll
    for (int j = 0; j < 8; j++) {
      int yy = yq + dyv[j], xx = xq + dxv[j];
      if (yy >= 0 && yy < HSZ && xx >= 0 && xx < WSZ) {
        float nb = ac * plane[yy * WSZ + xx] + bc;
        dot[j] += xc * nb;
      }
    }
    #pragma unroll
    for (int o = 0; o < NOUT; o++) acc[o] += wsm[o * CIN + c] * xc;
  }
  float cnc = cn[idx];
  #pragma unroll
  for (int j = 0; j < 8; j++) {
    int yy = yq + dyv[j], xx = xq + dxv[j];
    float cnn = (yy >= 0 && yy < HSZ && xx >= 0 && xx < WSZ)
                  ? cn[(b * HSZ + yy) * WSZ + xx] : 0.f;
    float sim = dot[j] / fmaxf(cnc * cnn, 1e-8f);
    #pragma unroll
    for (int o = 0; o < NOUT; o++) acc[o] += wsm[o * CIN + 64 + j] * sim;
  }
  #pragma unroll
  for (int o = 0; o < NOUT; o++) {
    float v;
    float* dst;
    int oo;
    if (o < half) { v = acc[o] * s_off[o] + b_off[o];        dst = out_off; oo = o; }
    else          { v = acc[o] * s_ds[o - half] + b_ds[o - half]; dst = out_ds; oo = o - half; }
    dst[((long)(b * half + oo)) * (HSZ * WSZ) + yq * WSZ + xq] = v;
  }
}

// ---------------- K5: combine off/gate + init_pos --------------------------
__global__ void k_combine(float* __restrict__ ws) {
  int idx = blockIdx.x * blockDim.x + threadIdx.x;   // B*32*HL*WL = 1048576
  int x = idx % WL;
  int y = (idx / WL) % HL;
  int c = (idx / (WL * HL)) % 32;
  int b = idx / (32 * HL * WL);
  const float* off_l = ws + WS_OFFL;
  const float* ds_l  = ws + WS_DSL;
  const float* off_h = ws + WS_OFFH;
  const float* ds_h  = ws + WS_DSH;
  float ol = off_l[idx];
  float dl = ds_l[idx];
  int ch = c >> 2, sdy = (c >> 1) & 1, sdx = c & 1;   // pixel_unshuffle mapping
  long hidx = ((long)(b * 8 + ch) * HH + (2 * y + sdy)) * WH + (2 * x + sdx);
  float o = ol + off_h[hidx];
  float d = dl + ds_h[hidx];
  float gate = 1.f / (1.f + expf(-d));
  int comp = c >> 4, sub = c & 15;
  int idy = (sub >> 1) & 1, idxb = sub & 1;
  float init = (comp == 0) ? (idxb ? 0.25f : -0.25f)
                           : (idy  ? 0.25f : -0.25f);
  ws[WS_OFFS + idx] = o * gate + init;
}

// ---------------- K6: bilinear sampler -------------------------------------
__global__ void k_sample(const float* __restrict__ feat, const float* __restrict__ offs,
                         float* __restrict__ out) {
  long idx = (long)blockIdx.x * blockDim.x + threadIdx.x;
  int X = idx & 255;
  int Y = (idx >> 8) & 255;
  int c = (idx >> 16) & 255;
  int b = (int)(idx >> 24);
  int g = c >> 6;
  int x = X >> 1, ddx = X & 1, y = Y >> 1, ddy = Y & 1;
  int sub = 4 * g + 2 * ddy + ddx;
  float offx = offs[((b * 32 + sub) * HL + y) * WL + x];
  float offy = offs[((b * 32 + 16 + sub) * HL + y) * WL + x];
  float gx = fminf(fmaxf((float)x + offx, 0.f), (float)(WL - 1));
  float gy = fminf(fmaxf((float)y + offy, 0.f), (float)(HL - 1));
  float fx0 = floorf(gx), fy0 = floorf(gy);
  int x0 = (int)fx0, y0 = (int)fy0;
  float wx = gx - fx0, wy = gy - fy0;
  int x1 = min(x0 + 1, WL - 1), y1 = min(y0 + 1, HL - 1);
  const float* plane = feat + ((long)(b * CFCH + c)) * (HL * WL);
  float v00 = plane[y0 * WL + x0], v01 = plane[y0 * WL + x1];
  float v10 = plane[y1 * WL + x0], v11 = plane[y1 * WL + x1];
  out[idx] = (v00 * (1.f - wx) + v01 * wx) * (1.f - wy)
           + (v10 * (1.f - wx) + v11 * wx) * wy;
}

extern "C" void kernel_launch(void* const* d_in, const int* in_sizes, int n_in,
                              void* d_out, int out_size, void* d_ws, size_t ws_size,
                              hipStream_t stream) {
  const float* x_l     = (const float*)d_in[0];
  const float* x_h     = (const float*)d_in[1];
  const float* feat    = (const float*)d_in[2];
  const float* gn_l_w  = (const float*)d_in[3];
  const float* gn_l_b  = (const float*)d_in[4];
  const float* gn_h_w  = (const float*)d_in[5];
  const float* gn_h_b  = (const float*)d_in[6];
  const float* w_off   = (const float*)d_in[7];
  const float* s_off   = (const float*)d_in[8];
  const float* b_off   = (const float*)d_in[9];
  const float* w_off_h = (const float*)d_in[10];
  const float* s_off_h = (const float*)d_in[11];
  const float* b_off_h = (const float*)d_in[12];
  const float* w_ds    = (const float*)d_in[13];
  const float* s_ds    = (const float*)d_in[14];
  const float* b_ds    = (const float*)d_in[15];
  const float* w_ds_h  = (const float*)d_in[16];
  const float* s_ds_h  = (const float*)d_in[17];
  const float* b_ds_h  = (const float*)d_in[18];
  float* ws  = (float*)d_ws;
  float* out = (float*)d_out;

  k_stats<<<32, 256, 0, stream>>>(x_l, x_h, gn_l_w, gn_l_b, gn_h_w, gn_h_b, ws);
  k_cn<<<640, 256, 0, stream>>>(x_l, x_h, ws);
  k_head<HL, WL, 64><<<(BATCH * HL * WL) / 256, 256, 0, stream>>>(
      x_l, w_off, w_ds, s_off, b_off, s_ds, b_ds,
      ws + WS_AL, ws + WS_BL, ws + WS_CNL, ws + WS_OFFL, ws + WS_DSL);
  k_head<HH, WH, 16><<<(BATCH * HH * WH) / 256, 256, 0, stream>>>(
      x_h, w_off_h, w_ds_h, s_off_h, b_off_h, s_ds_h, b_ds_h,
      ws + WS_AH, ws + WS_BH, ws + WS_CNH, ws + WS_OFFH, ws + WS_DSH);
  k_combine<<<(BATCH * 32 * HL * WL) / 256, 256, 0, stream>>>(ws);
  k_sample<<<(long)(BATCH * CFCH * HH * WH) / 256, 256, 0, stream>>>(feat, ws + WS_OFFS, out);
}

// Round 2
// 403.689 us; speedup vs baseline: 2.3574x; 2.3574x over previous
//
#include <hip/hip_runtime.h>
#include <math.h>

#define BATCH 2
#define CCH 64      // C
#define HL 128
#define WL 128
#define HH 256
#define WH 256
#define CFCH 256
#define CIN 72

// workspace layout (float offsets)
constexpr long WS_AL   = 0;                   // a_l   (B*C = 128)
constexpr long WS_BL   = 128;                 // bb_l
constexpr long WS_AH   = 256;                 // a_h
constexpr long WS_BH   = 384;                 // bb_h
constexpr long WS_CNL  = 512;                 // 2*128*128 = 32768
constexpr long WS_CNH  = WS_CNL + 32768;      // 2*256*256 = 131072
constexpr long WS_OFFL = WS_CNH + 131072;     // 2*32*128*128 = 1048576
constexpr long WS_DSL  = WS_OFFL + 1048576;
constexpr long WS_OFFH = WS_DSL + 1048576;    // 2*8*256*256 = 1048576
constexpr long WS_DSH  = WS_OFFH + 1048576;
constexpr long WS_OFFS = WS_DSH + 1048576;    // 2*32*128*128 = 1048576
constexpr long WS_PART = WS_OFFS + 1048576;   // 32 groups * 64 slices * 2

// ---------------- K1a: partial sums over 8192-element slices ----------------
// blocks 0..255: low  (16 groups x 16 slices)
// blocks 256..1279: high (16 groups x 64 slices)
__global__ void k_stats1(const float* __restrict__ xl, const float* __restrict__ xh,
                         float* __restrict__ ws) {
  int blk = blockIdx.x;
  const float* x;
  long base;
  int gg;   // global group index 0..31 (low 0..15, high 16..31)
  int slice;
  if (blk < 256) {
    int g = blk >> 4; slice = blk & 15;
    x = xl; gg = g;
    base = (long)g * 8 * (HL * WL) + (long)slice * 8192;
  } else {
    int id = blk - 256;
    int g = id >> 6; slice = id & 63;
    x = xh; gg = 16 + g;
    base = (long)g * 8 * (HH * WH) + (long)slice * 8192;
  }
  const float4* p = (const float4*)(x + base);
  float s = 0.f, s2 = 0.f;
  #pragma unroll
  for (int k = 0; k < 8; k++) {
    float4 v = p[threadIdx.x + k * 256];
    s  += v.x + v.y + v.z + v.w;
    s2 += v.x * v.x + v.y * v.y + v.z * v.z + v.w * v.w;
  }
  __shared__ float sh1[256], sh2[256];
  sh1[threadIdx.x] = s; sh2[threadIdx.x] = s2;
  __syncthreads();
  for (int off = 128; off > 0; off >>= 1) {
    if (threadIdx.x < off) {
      sh1[threadIdx.x] += sh1[threadIdx.x + off];
      sh2[threadIdx.x] += sh2[threadIdx.x + off];
    }
    __syncthreads();
  }
  if (threadIdx.x == 0) {
    int si = (blk < 256) ? slice : slice;
    ws[WS_PART + (gg * 64 + si) * 2]     = sh1[0];
    ws[WS_PART + (gg * 64 + si) * 2 + 1] = sh2[0];
  }
}

// ---------------- K1b: finalize per-channel affine coefficients -------------
__global__ void k_stats2(const float* __restrict__ gwl, const float* __restrict__ gbl,
                         const float* __restrict__ gwh, const float* __restrict__ gbh,
                         float* __restrict__ ws) {
  int blk = blockIdx.x;          // 0..31
  bool high = blk >= 16;
  int id = blk & 15;
  int b = id >> 3, g = id & 7;
  int gg = high ? 16 + id : id;
  int nsl = high ? 64 : 16;
  long n = high ? (long)8 * HH * WH : (long)8 * HL * WL;
  float s = 0.f, s2 = 0.f;
  for (int i = threadIdx.x; i < nsl; i += 64) {
    s  += ws[WS_PART + (gg * 64 + i) * 2];
    s2 += ws[WS_PART + (gg * 64 + i) * 2 + 1];
  }
  for (int off = 32; off > 0; off >>= 1) {
    s  += __shfl_down(s, off);
    s2 += __shfl_down(s2, off);
  }
  __shared__ float shm[2];
  if (threadIdx.x == 0) { shm[0] = s; shm[1] = s2; }
  __syncthreads();
  if (threadIdx.x < 8) {
    float mean = shm[0] / (float)n;
    float var  = shm[1] / (float)n - mean * mean;
    float inv  = rsqrtf(var + 1e-5f);
    int c = g * 8 + threadIdx.x;
    const float* gw = high ? gwh : gwl;
    const float* gb = high ? gbh : gbl;
    float a  = gw[c] * inv;
    float bb = gb[c] - mean * a;
    float* abase = ws + (high ? WS_AH : WS_AL);
    abase[b * CCH + c] = a;
    abase[128 + b * CCH + c] = bb;
  }
}

// ---------------- K2: per-pixel channel norms ------------------------------
__global__ void k_cn(const float* __restrict__ xl, const float* __restrict__ xh,
                     float* __restrict__ ws) {
  int idx = blockIdx.x * blockDim.x + threadIdx.x;
  const int nlow = BATCH * HL * WL;          // 32768
  const int ntot = nlow + BATCH * HH * WH;   // 163840
  if (idx >= ntot) return;
  if (idx < nlow) {
    int p = idx;
    int b = p / (HL * WL);
    int yx = p % (HL * WL);
    const float* a  = ws + WS_AL;
    const float* bb = ws + WS_BL;
    float s = 0.f;
    for (int c = 0; c < CCH; c++) {
      float v = a[b * CCH + c] * xl[((long)(b * CCH + c)) * (HL * WL) + yx] + bb[b * CCH + c];
      s += v * v;
    }
    ws[WS_CNL + p] = sqrtf(s);
  } else {
    int p = idx - nlow;
    int b = p / (HH * WH);
    int yx = p % (HH * WH);
    const float* a  = ws + WS_AH;
    const float* bb = ws + WS_BH;
    float s = 0.f;
    for (int c = 0; c < CCH; c++) {
      float v = a[b * CCH + c] * xh[((long)(b * CCH + c)) * (HH * WH) + yx] + bb[b * CCH + c];
      s += v * v;
    }
    ws[WS_CNH + p] = sqrtf(s);
  }
}

// ---------------- K3/K4: fused sim + conv1x1_bn heads ----------------------
template<int HSZ, int WSZ, int NOUT>
__global__ void k_head(const float* __restrict__ x,
                       const float* __restrict__ w_off, const float* __restrict__ w_ds,
                       const float* __restrict__ s_off, const float* __restrict__ b_off,
                       const float* __restrict__ s_ds,  const float* __restrict__ b_ds,
                       const float* __restrict__ acoef, const float* __restrict__ bcoef,
                       const float* __restrict__ cn,
                       float* __restrict__ out_off, float* __restrict__ out_ds) {
  __shared__ float wsm[NOUT * CIN];
  const int half = NOUT / 2;
  for (int i = threadIdx.x; i < NOUT * CIN; i += blockDim.x) {
    int o = i / CIN, c = i % CIN;
    wsm[i] = (o < half) ? w_off[o * CIN + c] : w_ds[(o - half) * CIN + c];
  }
  __syncthreads();
  int idx = blockIdx.x * blockDim.x + threadIdx.x;
  int xq = idx % WSZ;
  int yq = (idx / WSZ) % HSZ;
  int b  = idx / (WSZ * HSZ);
  float acc[NOUT];
  #pragma unroll
  for (int o = 0; o < NOUT; o++) acc[o] = 0.f;
  float dot[8];
  #pragma unroll
  for (int j = 0; j < 8; j++) dot[j] = 0.f;
  const int dyv[8] = {-2,-2,-2, 0, 0, 2, 2, 2};
  const int dxv[8] = {-2, 0, 2,-2, 2,-2, 0, 2};
  for (int c = 0; c < CCH; c++) {
    const float* plane = x + ((long)(b * CCH + c)) * (HSZ * WSZ);
    float ac = acoef[b * CCH + c], bc = bcoef[b * CCH + c];
    float xc = ac * plane[yq * WSZ + xq] + bc;
    #pragma unroll
    for (int j = 0; j < 8; j++) {
      int yy = yq + dyv[j], xx = xq + dxv[j];
      if (yy >= 0 && yy < HSZ && xx >= 0 && xx < WSZ) {
        float nb = ac * plane[yy * WSZ + xx] + bc;
        dot[j] += xc * nb;
      }
    }
    #pragma unroll
    for (int o = 0; o < NOUT; o++) acc[o] += wsm[o * CIN + c] * xc;
  }
  float cnc = cn[idx];
  #pragma unroll
  for (int j = 0; j < 8; j++) {
    int yy = yq + dyv[j], xx = xq + dxv[j];
    float cnn = (yy >= 0 && yy < HSZ && xx >= 0 && xx < WSZ)
                  ? cn[(b * HSZ + yy) * WSZ + xx] : 0.f;
    float sim = dot[j] / fmaxf(cnc * cnn, 1e-8f);
    #pragma unroll
    for (int o = 0; o < NOUT; o++) acc[o] += wsm[o * CIN + 64 + j] * sim;
  }
  #pragma unroll
  for (int o = 0; o < NOUT; o++) {
    float v;
    float* dst;
    int oo;
    if (o < half) { v = acc[o] * s_off[o] + b_off[o];        dst = out_off; oo = o; }
    else          { v = acc[o] * s_ds[o - half] + b_ds[o - half]; dst = out_ds; oo = o - half; }
    dst[((long)(b * half + oo)) * (HSZ * WSZ) + yq * WSZ + xq] = v;
  }
}

// ---------------- K5: combine off/gate + init_pos --------------------------
__global__ void k_combine(float* __restrict__ ws) {
  int idx = blockIdx.x * blockDim.x + threadIdx.x;   // B*32*HL*WL = 1048576
  int x = idx % WL;
  int y = (idx / WL) % HL;
  int c = (idx / (WL * HL)) % 32;
  int b = idx / (32 * HL * WL);
  const float* off_l = ws + WS_OFFL;
  const float* ds_l  = ws + WS_DSL;
  const float* off_h = ws + WS_OFFH;
  const float* ds_h  = ws + WS_DSH;
  float ol = off_l[idx];
  float dl = ds_l[idx];
  int ch = c >> 2, sdy = (c >> 1) & 1, sdx = c & 1;
  long hidx = ((long)(b * 8 + ch) * HH + (2 * y + sdy)) * WH + (2 * x + sdx);
  float o = ol + off_h[hidx];
  float d = dl + ds_h[hidx];
  float gate = 1.f / (1.f + expf(-d));
  int comp = c >> 4, sub = c & 15;
  int idy = (sub >> 1) & 1, idxb = sub & 1;
  float init = (comp == 0) ? (idxb ? 0.25f : -0.25f)
                           : (idy  ? 0.25f : -0.25f);
  ws[WS_OFFS + idx] = o * gate + init;
}

// ---------------- K6: bilinear sampler -------------------------------------
__global__ void k_sample(const float* __restrict__ feat, const float* __restrict__ offs,
                         float* __restrict__ out) {
  long idx = (long)blockIdx.x * blockDim.x + threadIdx.x;
  int X = idx & 255;
  int Y = (idx >> 8) & 255;
  int c = (idx >> 16) & 255;
  int b = (int)(idx >> 24);
  int g = c >> 6;
  int x = X >> 1, ddx = X & 1, y = Y >> 1, ddy = Y & 1;
  int sub = 4 * g + 2 * ddy + ddx;
  float offx = offs[((b * 32 + sub) * HL + y) * WL + x];
  float offy = offs[((b * 32 + 16 + sub) * HL + y) * WL + x];
  float gx = fminf(fmaxf((float)x + offx, 0.f), (float)(WL - 1));
  float gy = fminf(fmaxf((float)y + offy, 0.f), (float)(HL - 1));
  float fx0 = floorf(gx), fy0 = floorf(gy);
  int x0 = (int)fx0, y0 = (int)fy0;
  float wx = gx - fx0, wy = gy - fy0;
  int x1 = min(x0 + 1, WL - 1), y1 = min(y0 + 1, HL - 1);
  const float* plane = feat + ((long)(b * CFCH + c)) * (HL * WL);
  float v00 = plane[y0 * WL + x0], v01 = plane[y0 * WL + x1];
  float v10 = plane[y1 * WL + x0], v11 = plane[y1 * WL + x1];
  out[idx] = (v00 * (1.f - wx) + v01 * wx) * (1.f - wy)
           + (v10 * (1.f - wx) + v11 * wx) * wy;
}

extern "C" void kernel_launch(void* const* d_in, const int* in_sizes, int n_in,
                              void* d_out, int out_size, void* d_ws, size_t ws_size,
                              hipStream_t stream) {
  const float* x_l     = (const float*)d_in[0];
  const float* x_h     = (const float*)d_in[1];
  const float* feat    = (const float*)d_in[2];
  const float* gn_l_w  = (const float*)d_in[3];
  const float* gn_l_b  = (const float*)d_in[4];
  const float* gn_h_w  = (const float*)d_in[5];
  const float* gn_h_b  = (const float*)d_in[6];
  const float* w_off   = (const float*)d_in[7];
  const float* s_off   = (const float*)d_in[8];
  const float* b_off   = (const float*)d_in[9];
  const float* w_off_h = (const float*)d_in[10];
  const float* s_off_h = (const float*)d_in[11];
  const float* b_off_h = (const float*)d_in[12];
  const float* w_ds    = (const float*)d_in[13];
  const float* s_ds    = (const float*)d_in[14];
  const float* b_ds    = (const float*)d_in[15];
  const float* w_ds_h  = (const float*)d_in[16];
  const float* s_ds_h  = (const float*)d_in[17];
  const float* b_ds_h  = (const float*)d_in[18];
  float* ws  = (float*)d_ws;
  float* out = (float*)d_out;

  k_stats1<<<1280, 256, 0, stream>>>(x_l, x_h, ws);
  k_stats2<<<32, 64, 0, stream>>>(gn_l_w, gn_l_b, gn_h_w, gn_h_b, ws);
  k_cn<<<640, 256, 0, stream>>>(x_l, x_h, ws);
  k_head<HL, WL, 64><<<(BATCH * HL * WL) / 256, 256, 0, stream>>>(
      x_l, w_off, w_ds, s_off, b_off, s_ds, b_ds,
      ws + WS_AL, ws + WS_BL, ws + WS_CNL, ws + WS_OFFL, ws + WS_DSL);
  k_head<HH, WH, 16><<<(BATCH * HH * WH) / 256, 256, 0, stream>>>(
      x_h, w_off_h, w_ds_h, s_off_h, b_off_h, s_ds_h, b_ds_h,
      ws + WS_AH, ws + WS_BH, ws + WS_CNH, ws + WS_OFFH, ws + WS_DSH);
  k_combine<<<(BATCH * 32 * HL * WL) / 256, 256, 0, stream>>>(ws);
  k_sample<<<(long)(BATCH * CFCH * HH * WH) / 256, 256, 0, stream>>>(feat, ws + WS_OFFS, out);
}

// Round 3
// 308.147 us; speedup vs baseline: 3.0883x; 1.3101x over previous
//
#include <hip/hip_runtime.h>
#include <math.h>

#define BATCH 2
#define CCH 64      // C
#define HL 128
#define WL 128
#define HH 256
#define WH 256
#define CFCH 256
#define CIN 72

// workspace layout (float offsets)
constexpr long WS_AL   = 0;                   // a_l   (B*C = 128)
constexpr long WS_BL   = 128;                 // bb_l
constexpr long WS_AH   = 256;                 // a_h
constexpr long WS_BH   = 384;                 // bb_h
constexpr long WS_CNL  = 512;                 // 2*128*128 = 32768
constexpr long WS_CNH  = WS_CNL + 32768;      // 2*256*256 = 131072
constexpr long WS_OFFL = WS_CNH + 131072;     // 2*32*128*128 = 1048576
constexpr long WS_DSL  = WS_OFFL + 1048576;
constexpr long WS_OFFH = WS_DSL + 1048576;    // 2*8*256*256 = 1048576
constexpr long WS_DSH  = WS_OFFH + 1048576;
constexpr long WS_OFFS = WS_DSH + 1048576;    // 2*32*128*128 = 1048576
constexpr long WS_PART = WS_OFFS + 1048576;   // 32 groups * 64 slices * 2

// ---------------- K1a: partial sums over 8192-element slices ----------------
__global__ void k_stats1(const float* __restrict__ xl, const float* __restrict__ xh,
                         float* __restrict__ ws) {
  int blk = blockIdx.x;
  const float* x;
  long base;
  int gg, slice;
  if (blk < 256) {
    int g = blk >> 4; slice = blk & 15;
    x = xl; gg = g;
    base = (long)g * 8 * (HL * WL) + (long)slice * 8192;
  } else {
    int id = blk - 256;
    int g = id >> 6; slice = id & 63;
    x = xh; gg = 16 + g;
    base = (long)g * 8 * (HH * WH) + (long)slice * 8192;
  }
  const float4* p = (const float4*)(x + base);
  float s = 0.f, s2 = 0.f;
  #pragma unroll
  for (int k = 0; k < 8; k++) {
    float4 v = p[threadIdx.x + k * 256];
    s  += v.x + v.y + v.z + v.w;
    s2 += v.x * v.x + v.y * v.y + v.z * v.z + v.w * v.w;
  }
  __shared__ float sh1[256], sh2[256];
  sh1[threadIdx.x] = s; sh2[threadIdx.x] = s2;
  __syncthreads();
  for (int off = 128; off > 0; off >>= 1) {
    if (threadIdx.x < off) {
      sh1[threadIdx.x] += sh1[threadIdx.x + off];
      sh2[threadIdx.x] += sh2[threadIdx.x + off];
    }
    __syncthreads();
  }
  if (threadIdx.x == 0) {
    ws[WS_PART + (gg * 64 + slice) * 2]     = sh1[0];
    ws[WS_PART + (gg * 64 + slice) * 2 + 1] = sh2[0];
  }
}

// ---------------- K1b: finalize per-channel affine coefficients -------------
__global__ void k_stats2(const float* __restrict__ gwl, const float* __restrict__ gbl,
                         const float* __restrict__ gwh, const float* __restrict__ gbh,
                         float* __restrict__ ws) {
  int blk = blockIdx.x;          // 0..31
  bool high = blk >= 16;
  int id = blk & 15;
  int b = id >> 3, g = id & 7;
  int gg = high ? 16 + id : id;
  int nsl = high ? 64 : 16;
  long n = high ? (long)8 * HH * WH : (long)8 * HL * WL;
  float s = 0.f, s2 = 0.f;
  for (int i = threadIdx.x; i < nsl; i += 64) {
    s  += ws[WS_PART + (gg * 64 + i) * 2];
    s2 += ws[WS_PART + (gg * 64 + i) * 2 + 1];
  }
  for (int off = 32; off > 0; off >>= 1) {
    s  += __shfl_down(s, off);
    s2 += __shfl_down(s2, off);
  }
  __shared__ float shm[2];
  if (threadIdx.x == 0) { shm[0] = s; shm[1] = s2; }
  __syncthreads();
  if (threadIdx.x < 8) {
    float mean = shm[0] / (float)n;
    float var  = shm[1] / (float)n - mean * mean;
    float inv  = rsqrtf(var + 1e-5f);
    int c = g * 8 + threadIdx.x;
    const float* gw = high ? gwh : gwl;
    const float* gb = high ? gbh : gbl;
    float a  = gw[c] * inv;
    float bb = gb[c] - mean * a;
    float* abase = ws + (high ? WS_AH : WS_AL);
    abase[b * CCH + c] = a;
    abase[128 + b * CCH + c] = bb;
  }
}

// ---------------- K2: per-pixel channel norms ------------------------------
__global__ void k_cn(const float* __restrict__ xl, const float* __restrict__ xh,
                     float* __restrict__ ws) {
  int idx = blockIdx.x * blockDim.x + threadIdx.x;
  const int nlow = BATCH * HL * WL;
  const int ntot = nlow + BATCH * HH * WH;
  if (idx >= ntot) return;
  if (idx < nlow) {
    int p = idx;
    int b = p / (HL * WL);
    int yx = p % (HL * WL);
    const float* a  = ws + WS_AL;
    const float* bb = ws + WS_BL;
    float s = 0.f;
    for (int c = 0; c < CCH; c++) {
      float v = a[b * CCH + c] * xl[((long)(b * CCH + c)) * (HL * WL) + yx] + bb[b * CCH + c];
      s += v * v;
    }
    ws[WS_CNL + p] = sqrtf(s);
  } else {
    int p = idx - nlow;
    int b = p / (HH * WH);
    int yx = p % (HH * WH);
    const float* a  = ws + WS_AH;
    const float* bb = ws + WS_BH;
    float s = 0.f;
    for (int c = 0; c < CCH; c++) {
      float v = a[b * CCH + c] * xh[((long)(b * CCH + c)) * (HH * WH) + yx] + bb[b * CCH + c];
      s += v * v;
    }
    ws[WS_CNH + p] = sqrtf(s);
  }
}

// ---------------- K3/K4: fused sim + conv1x1_bn heads ----------------------
// 4 threads (= 4 waves) per pixel, 64 pixels per block.
// wave t: computes neighbor dots 2t,2t+1 for its pixel, then outputs [t*PER, (t+1)*PER)
template<int HSZ, int WSZ, int NOUT>
__global__ __launch_bounds__(256) void k_head(
                       const float* __restrict__ x,
                       const float* __restrict__ w_off, const float* __restrict__ w_ds,
                       const float* __restrict__ s_off, const float* __restrict__ b_off,
                       const float* __restrict__ s_ds,  const float* __restrict__ b_ds,
                       const float* __restrict__ acoef, const float* __restrict__ bcoef,
                       const float* __restrict__ cn,
                       float* __restrict__ out_off, float* __restrict__ out_ds) {
  constexpr int half = NOUT / 2;
  constexpr int PER  = NOUT / 4;
  __shared__ float wsm[NOUT * CIN];
  __shared__ float sim_lds[64 * 9];
  __shared__ float asm_[CCH], bsm_[CCH];
  for (int i = threadIdx.x; i < NOUT * CIN; i += 256) {
    int o = i / CIN, c = i % CIN;
    wsm[i] = (o < half) ? w_off[o * CIN + c] : w_ds[(o - half) * CIN + c];
  }
  int px = threadIdx.x & 63;
  int t  = threadIdx.x >> 6;        // wave index, wave-uniform
  int gpix = blockIdx.x * 64 + px;  // 64 consecutive x within one row
  int xq = gpix % WSZ;
  int yq = (gpix / WSZ) % HSZ;
  int b  = gpix / (WSZ * HSZ);      // uniform per block
  if (threadIdx.x < CCH)            asm_[threadIdx.x] = acoef[b * CCH + threadIdx.x];
  else if (threadIdx.x < 2 * CCH)   bsm_[threadIdx.x - CCH] = bcoef[b * CCH + threadIdx.x - CCH];
  __syncthreads();

  // neighbor pair for this wave
  int dy0, dx0, dy1, dx1;
  switch (t) {
    case 0: dy0 = -2; dx0 = -2; dy1 = -2; dx1 =  0; break;
    case 1: dy0 = -2; dx0 =  2; dy1 =  0; dx1 = -2; break;
    case 2: dy0 =  0; dx0 =  2; dy1 =  2; dx1 = -2; break;
    default:dy0 =  2; dx0 =  0; dy1 =  2; dx1 =  2; break;
  }
  int yn0 = yq + dy0, xn0 = xq + dx0;
  int yn1 = yq + dy1, xn1 = xq + dx1;
  bool ok0 = (yn0 >= 0 && yn0 < HSZ && xn0 >= 0 && xn0 < WSZ);
  bool ok1 = (yn1 >= 0 && yn1 < HSZ && xn1 >= 0 && xn1 < WSZ);
  const float* base = x + ((long)b * CCH) * (HSZ * WSZ) + yq * WSZ + xq;
  long noff0 = (long)dy0 * WSZ + dx0;
  long noff1 = (long)dy1 * WSZ + dx1;

  float xc[CCH];
  float dot0 = 0.f, dot1 = 0.f;
  #pragma unroll
  for (int c = 0; c < CCH; c++) {
    const float* p = base + (long)c * (HSZ * WSZ);
    float ac = asm_[c], bc = bsm_[c];
    float v = ac * p[0] + bc;
    xc[c] = v;
    if (ok0) dot0 += v * (ac * p[noff0] + bc);
    if (ok1) dot1 += v * (ac * p[noff1] + bc);
  }
  float cnc = cn[gpix];
  float cnn0 = ok0 ? cn[(b * HSZ + yn0) * WSZ + xn0] : 0.f;
  float cnn1 = ok1 ? cn[(b * HSZ + yn1) * WSZ + xn1] : 0.f;
  sim_lds[px * 9 + 2 * t]     = dot0 / fmaxf(cnc * cnn0, 1e-8f);
  sim_lds[px * 9 + 2 * t + 1] = dot1 / fmaxf(cnc * cnn1, 1e-8f);
  __syncthreads();

  float sims[8];
  #pragma unroll
  for (int j = 0; j < 8; j++) sims[j] = sim_lds[px * 9 + j];

  #pragma unroll
  for (int ol = 0; ol < PER; ol++) {
    int o = t * PER + ol;           // wave-uniform
    float acc = 0.f;
    #pragma unroll
    for (int c = 0; c < CCH; c++) acc += wsm[o * CIN + c] * xc[c];
    #pragma unroll
    for (int j = 0; j < 8; j++) acc += wsm[o * CIN + 64 + j] * sims[j];
    float v;
    float* dst;
    int oo;
    if (o < half) { v = acc * s_off[o] + b_off[o];               dst = out_off; oo = o; }
    else          { v = acc * s_ds[o - half] + b_ds[o - half];   dst = out_ds;  oo = o - half; }
    dst[((long)(b * half + oo)) * (HSZ * WSZ) + yq * WSZ + xq] = v;
  }
}

// ---------------- K5: combine off/gate + init_pos --------------------------
__global__ void k_combine(float* __restrict__ ws) {
  int idx = blockIdx.x * blockDim.x + threadIdx.x;   // B*32*HL*WL = 1048576
  int x = idx % WL;
  int y = (idx / WL) % HL;
  int c = (idx / (WL * HL)) % 32;
  int b = idx / (32 * HL * WL);
  const float* off_l = ws + WS_OFFL;
  const float* ds_l  = ws + WS_DSL;
  const float* off_h = ws + WS_OFFH;
  const float* ds_h  = ws + WS_DSH;
  float ol = off_l[idx];
  float dl = ds_l[idx];
  int ch = c >> 2, sdy = (c >> 1) & 1, sdx = c & 1;
  long hidx = ((long)(b * 8 + ch) * HH + (2 * y + sdy)) * WH + (2 * x + sdx);
  float o = ol + off_h[hidx];
  float d = dl + ds_h[hidx];
  float gate = 1.f / (1.f + expf(-d));
  int comp = c >> 4, sub = c & 15;
  int idy = (sub >> 1) & 1, idxb = sub & 1;
  float init = (comp == 0) ? (idxb ? 0.25f : -0.25f)
                           : (idy  ? 0.25f : -0.25f);
  ws[WS_OFFS + idx] = o * gate + init;
}

// ---------------- K6: bilinear sampler -------------------------------------
__global__ void k_sample(const float* __restrict__ feat, const float* __restrict__ offs,
                         float* __restrict__ out) {
  long idx = (long)blockIdx.x * blockDim.x + threadIdx.x;
  int X = idx & 255;
  int Y = (idx >> 8) & 255;
  int c = (idx >> 16) & 255;
  int b = (int)(idx >> 24);
  int g = c >> 6;
  int x = X >> 1, ddx = X & 1, y = Y >> 1, ddy = Y & 1;
  int sub = 4 * g + 2 * ddy + ddx;
  float offx = offs[((b * 32 + sub) * HL + y) * WL + x];
  float offy = offs[((b * 32 + 16 + sub) * HL + y) * WL + x];
  float gx = fminf(fmaxf((float)x + offx, 0.f), (float)(WL - 1));
  float gy = fminf(fmaxf((float)y + offy, 0.f), (float)(HL - 1));
  float fx0 = floorf(gx), fy0 = floorf(gy);
  int x0 = (int)fx0, y0 = (int)fy0;
  float wx = gx - fx0, wy = gy - fy0;
  int x1 = min(x0 + 1, WL - 1), y1 = min(y0 + 1, HL - 1);
  const float* plane = feat + ((long)(b * CFCH + c)) * (HL * WL);
  float v00 = plane[y0 * WL + x0], v01 = plane[y0 * WL + x1];
  float v10 = plane[y1 * WL + x0], v11 = plane[y1 * WL + x1];
  out[idx] = (v00 * (1.f - wx) + v01 * wx) * (1.f - wy)
           + (v10 * (1.f - wx) + v11 * wx) * wy;
}

extern "C" void kernel_launch(void* const* d_in, const int* in_sizes, int n_in,
                              void* d_out, int out_size, void* d_ws, size_t ws_size,
                              hipStream_t stream) {
  const float* x_l     = (const float*)d_in[0];
  const float* x_h     = (const float*)d_in[1];
  const float* feat    = (const float*)d_in[2];
  const float* gn_l_w  = (const float*)d_in[3];
  const float* gn_l_b  = (const float*)d_in[4];
  const float* gn_h_w  = (const float*)d_in[5];
  const float* gn_h_b  = (const float*)d_in[6];
  const float* w_off   = (const float*)d_in[7];
  const float* s_off   = (const float*)d_in[8];
  const float* b_off   = (const float*)d_in[9];
  const float* w_off_h = (const float*)d_in[10];
  const float* s_off_h = (const float*)d_in[11];
  const float* b_off_h = (const float*)d_in[12];
  const float* w_ds    = (const float*)d_in[13];
  const float* s_ds    = (const float*)d_in[14];
  const float* b_ds    = (const float*)d_in[15];
  const float* w_ds_h  = (const float*)d_in[16];
  const float* s_ds_h  = (const float*)d_in[17];
  const float* b_ds_h  = (const float*)d_in[18];
  float* ws  = (float*)d_ws;
  float* out = (float*)d_out;

  k_stats1<<<1280, 256, 0, stream>>>(x_l, x_h, ws);
  k_stats2<<<32, 64, 0, stream>>>(gn_l_w, gn_l_b, gn_h_w, gn_h_b, ws);
  k_cn<<<640, 256, 0, stream>>>(x_l, x_h, ws);
  k_head<HL, WL, 64><<<(BATCH * HL * WL) / 64, 256, 0, stream>>>(
      x_l, w_off, w_ds, s_off, b_off, s_ds, b_ds,
      ws + WS_AL, ws + WS_BL, ws + WS_CNL, ws + WS_OFFL, ws + WS_DSL);
  k_head<HH, WH, 16><<<(BATCH * HH * WH) / 64, 256, 0, stream>>>(
      x_h, w_off_h, w_ds_h, s_off_h, b_off_h, s_ds_h, b_ds_h,
      ws + WS_AH, ws + WS_BH, ws + WS_CNH, ws + WS_OFFH, ws + WS_DSH);
  k_combine<<<(BATCH * 32 * HL * WL) / 256, 256, 0, stream>>>(ws);
  k_sample<<<(long)(BATCH * CFCH * HH * WH) / 256, 256, 0, stream>>>(feat, ws + WS_OFFS, out);
}

// Round 4
// 155.447 us; speedup vs baseline: 6.1219x; 1.9823x over previous
//
#include <hip/hip_runtime.h>
#include <math.h>

#define BATCH 2
#define CCH 64      // C
#define HL 128
#define WL 128
#define HH 256
#define WH 256
#define CFCH 256
#define CIN 72

// workspace layout (float offsets)
constexpr long WS_AL   = 0;                   // a_l   (B*C = 128)
constexpr long WS_BL   = 128;                 // bb_l
constexpr long WS_AH   = 256;                 // a_h
constexpr long WS_BH   = 384;                 // bb_h
constexpr long WS_CNL  = 512;                 // (unused now)
constexpr long WS_CNH  = WS_CNL + 32768;
constexpr long WS_OFFL = WS_CNH + 131072;     // 2*32*128*128 = 1048576
constexpr long WS_DSL  = WS_OFFL + 1048576;
constexpr long WS_OFFH = WS_DSL + 1048576;    // 2*8*256*256 = 1048576
constexpr long WS_DSH  = WS_OFFH + 1048576;
constexpr long WS_OFFS = WS_DSH + 1048576;    // 2*32*128*128 = 1048576
constexpr long WS_PART = WS_OFFS + 1048576;   // 32 groups * 64 slices * 2

// ---------------- K1a: partial sums over 8192-element slices ----------------
__global__ void k_stats1(const float* __restrict__ xl, const float* __restrict__ xh,
                         float* __restrict__ ws) {
  int blk = blockIdx.x;
  const float* x;
  long base;
  int gg, slice;
  if (blk < 256) {
    int g = blk >> 4; slice = blk & 15;
    x = xl; gg = g;
    base = (long)g * 8 * (HL * WL) + (long)slice * 8192;
  } else {
    int id = blk - 256;
    int g = id >> 6; slice = id & 63;
    x = xh; gg = 16 + g;
    base = (long)g * 8 * (HH * WH) + (long)slice * 8192;
  }
  const float4* p = (const float4*)(x + base);
  float s = 0.f, s2 = 0.f;
  #pragma unroll
  for (int k = 0; k < 8; k++) {
    float4 v = p[threadIdx.x + k * 256];
    s  += v.x + v.y + v.z + v.w;
    s2 += v.x * v.x + v.y * v.y + v.z * v.z + v.w * v.w;
  }
  __shared__ float sh1[256], sh2[256];
  sh1[threadIdx.x] = s; sh2[threadIdx.x] = s2;
  __syncthreads();
  for (int off = 128; off > 0; off >>= 1) {
    if (threadIdx.x < off) {
      sh1[threadIdx.x] += sh1[threadIdx.x + off];
      sh2[threadIdx.x] += sh2[threadIdx.x + off];
    }
    __syncthreads();
  }
  if (threadIdx.x == 0) {
    ws[WS_PART + (gg * 64 + slice) * 2]     = sh1[0];
    ws[WS_PART + (gg * 64 + slice) * 2 + 1] = sh2[0];
  }
}

// ---------------- K1b: finalize per-channel affine coefficients -------------
__global__ void k_stats2(const float* __restrict__ gwl, const float* __restrict__ gbl,
                         const float* __restrict__ gwh, const float* __restrict__ gbh,
                         float* __restrict__ ws) {
  int blk = blockIdx.x;          // 0..31
  bool high = blk >= 16;
  int id = blk & 15;
  int b = id >> 3, g = id & 7;
  int gg = high ? 16 + id : id;
  int nsl = high ? 64 : 16;
  long n = high ? (long)8 * HH * WH : (long)8 * HL * WL;
  float s = 0.f, s2 = 0.f;
  for (int i = threadIdx.x; i < nsl; i += 64) {
    s  += ws[WS_PART + (gg * 64 + i) * 2];
    s2 += ws[WS_PART + (gg * 64 + i) * 2 + 1];
  }
  for (int off = 32; off > 0; off >>= 1) {
    s  += __shfl_down(s, off);
    s2 += __shfl_down(s2, off);
  }
  __shared__ float shm[2];
  if (threadIdx.x == 0) { shm[0] = s; shm[1] = s2; }
  __syncthreads();
  if (threadIdx.x < 8) {
    float mean = shm[0] / (float)n;
    float var  = shm[1] / (float)n - mean * mean;
    float inv  = rsqrtf(var + 1e-5f);
    int c = g * 8 + threadIdx.x;
    const float* gw = high ? gwh : gwl;
    const float* gb = high ? gbh : gbl;
    float a  = gw[c] * inv;
    float bb = gb[c] - mean * a;
    float* abase = ws + (high ? WS_AH : WS_AL);
    abase[b * CCH + c] = a;
    abase[128 + b * CCH + c] = bb;
  }
}

// ---------------- K3/K4: fused sim + conv1x1_bn heads ----------------------
// 512 threads = 8 waves; 64 pixels per block (contiguous in one row).
// Phase 0: build normalized center tile xc[64ch][64px] in LDS + per-pixel sumsq.
// Phase 1: wave t computes neighbor t's dot & norm; sim -> LDS.
// Phase 2: wave t computes outputs [t*PER, (t+1)*PER).
template<int HSZ, int WSZ, int NOUT>
__global__ __launch_bounds__(512) void k_head(
                       const float* __restrict__ x,
                       const float* __restrict__ w_off, const float* __restrict__ w_ds,
                       const float* __restrict__ s_off, const float* __restrict__ b_off,
                       const float* __restrict__ s_ds,  const float* __restrict__ b_ds,
                       const float* __restrict__ acoef, const float* __restrict__ bcoef,
                       float* __restrict__ out_off, float* __restrict__ out_ds) {
  constexpr int HW   = HSZ * WSZ;
  constexpr int half = NOUT / 2;
  constexpr int PER  = NOUT / 8;
  __shared__ float wsm[NOUT * CIN];
  __shared__ float xc[CCH * 64];
  __shared__ float psum[8 * 64];
  __shared__ float sims[8 * 64];
  __shared__ float asm_[CCH], bsm_[CCH];

  int tid = threadIdx.x;
  int px = tid & 63;
  int t  = tid >> 6;                 // wave index 0..7, wave-uniform
  int gpix = blockIdx.x * 64 + px;
  int xq = gpix % WSZ;
  int yq = (gpix / WSZ) % HSZ;
  int bq = gpix / (WSZ * HSZ);       // uniform per block

  for (int i = tid; i < NOUT * CIN; i += 512) {
    int o = i / CIN, c = i % CIN;
    wsm[i] = (o < half) ? w_off[o * CIN + c] : w_ds[(o - half) * CIN + c];
  }
  if (tid < CCH)            asm_[tid] = acoef[bq * CCH + tid];
  else if (tid < 2 * CCH)   bsm_[tid - CCH] = bcoef[bq * CCH + tid - CCH];
  __syncthreads();

  const float* ptr = x + ((long)(bq * CCH)) * HW + yq * WSZ + xq;

  // phase 0: center tile + sumsq partials
  {
    float ss = 0.f;
    #pragma unroll
    for (int k = 0; k < 8; k++) {
      int c = t * 8 + k;
      float v = fmaf(asm_[c], ptr[(long)c * HW], bsm_[c]);
      xc[c * 64 + px] = v;
      ss += v * v;
    }
    psum[t * 64 + px] = ss;
  }
  __syncthreads();

  // phase 1: neighbor t
  {
    const int dyv[8] = {-2,-2,-2, 0, 0, 2, 2, 2};
    const int dxv[8] = {-2, 0, 2,-2, 2,-2, 0, 2};
    int dy = dyv[t], dx = dxv[t];
    int yn = yq + dy;                // uniform
    int xn = xq + dx;                // per-lane
    bool ok = (yn >= 0 && yn < HSZ && xn >= 0 && xn < WSZ);
    float dot = 0.f, nbq = 0.f;
    if (ok) {
      const float* nptr = ptr + (long)dy * WSZ + dx;
      #pragma unroll 16
      for (int c = 0; c < CCH; c++) {
        float nb = fmaf(asm_[c], nptr[(long)c * HW], bsm_[c]);
        float xv = xc[c * 64 + px];
        dot += xv * nb;
        nbq += nb * nb;
      }
    }
    float cs = 0.f;
    #pragma unroll
    for (int tt = 0; tt < 8; tt++) cs += psum[tt * 64 + px];
    float cnc = sqrtf(cs);
    sims[t * 64 + px] = dot / fmaxf(cnc * sqrtf(nbq), 1e-8f);
  }
  __syncthreads();

  // phase 2: conv outputs for this wave
  {
    float sv[8];
    #pragma unroll
    for (int j = 0; j < 8; j++) sv[j] = sims[j * 64 + px];
    float acc[PER];
    #pragma unroll
    for (int ol = 0; ol < PER; ol++) acc[ol] = 0.f;
    int o0 = t * PER;
    #pragma unroll 4
    for (int c = 0; c < CCH; c += 4) {
      float x0v = xc[(c + 0) * 64 + px];
      float x1v = xc[(c + 1) * 64 + px];
      float x2v = xc[(c + 2) * 64 + px];
      float x3v = xc[(c + 3) * 64 + px];
      #pragma unroll
      for (int ol = 0; ol < PER; ol++) {
        const float4 w4 = *(const float4*)&wsm[(o0 + ol) * CIN + c];
        acc[ol] += w4.x * x0v + w4.y * x1v + w4.z * x2v + w4.w * x3v;
      }
    }
    #pragma unroll
    for (int ol = 0; ol < PER; ol++) {
      const float4 wa = *(const float4*)&wsm[(o0 + ol) * CIN + 64];
      const float4 wb = *(const float4*)&wsm[(o0 + ol) * CIN + 68];
      acc[ol] += wa.x * sv[0] + wa.y * sv[1] + wa.z * sv[2] + wa.w * sv[3]
               + wb.x * sv[4] + wb.y * sv[5] + wb.z * sv[6] + wb.w * sv[7];
    }
    #pragma unroll
    for (int ol = 0; ol < PER; ol++) {
      int o = o0 + ol;
      float v;
      float* dst;
      int oo;
      if (o < half) { v = acc[ol] * s_off[o] + b_off[o];             dst = out_off; oo = o; }
      else          { v = acc[ol] * s_ds[o - half] + b_ds[o - half]; dst = out_ds;  oo = o - half; }
      dst[((long)(bq * half + oo)) * HW + yq * WSZ + xq] = v;
    }
  }
}

// ---------------- K5: combine off/gate + init_pos --------------------------
__global__ void k_combine(float* __restrict__ ws) {
  int idx = blockIdx.x * blockDim.x + threadIdx.x;   // B*32*HL*WL = 1048576
  int x = idx % WL;
  int y = (idx / WL) % HL;
  int c = (idx / (WL * HL)) % 32;
  int b = idx / (32 * HL * WL);
  const float* off_l = ws + WS_OFFL;
  const float* ds_l  = ws + WS_DSL;
  const float* off_h = ws + WS_OFFH;
  const float* ds_h  = ws + WS_DSH;
  float ol = off_l[idx];
  float dl = ds_l[idx];
  int ch = c >> 2, sdy = (c >> 1) & 1, sdx = c & 1;
  long hidx = ((long)(b * 8 + ch) * HH + (2 * y + sdy)) * WH + (2 * x + sdx);
  float o = ol + off_h[hidx];
  float d = dl + ds_h[hidx];
  float gate = 1.f / (1.f + expf(-d));
  int comp = c >> 4, sub = c & 15;
  int idy = (sub >> 1) & 1, idxb = sub & 1;
  float init = (comp == 0) ? (idxb ? 0.25f : -0.25f)
                           : (idy  ? 0.25f : -0.25f);
  ws[WS_OFFS + idx] = o * gate + init;
}

// ---------------- K6: bilinear sampler -------------------------------------
__global__ void k_sample(const float* __restrict__ feat, const float* __restrict__ offs,
                         float* __restrict__ out) {
  long idx = (long)blockIdx.x * blockDim.x + threadIdx.x;
  int X = idx & 255;
  int Y = (idx >> 8) & 255;
  int c = (idx >> 16) & 255;
  int b = (int)(idx >> 24);
  int g = c >> 6;
  int x = X >> 1, ddx = X & 1, y = Y >> 1, ddy = Y & 1;
  int sub = 4 * g + 2 * ddy + ddx;
  float offx = offs[((b * 32 + sub) * HL + y) * WL + x];
  float offy = offs[((b * 32 + 16 + sub) * HL + y) * WL + x];
  float gx = fminf(fmaxf((float)x + offx, 0.f), (float)(WL - 1));
  float gy = fminf(fmaxf((float)y + offy, 0.f), (float)(HL - 1));
  float fx0 = floorf(gx), fy0 = floorf(gy);
  int x0 = (int)fx0, y0 = (int)fy0;
  float wx = gx - fx0, wy = gy - fy0;
  int x1 = min(x0 + 1, WL - 1), y1 = min(y0 + 1, HL - 1);
  const float* plane = feat + ((long)(b * CFCH + c)) * (HL * WL);
  float v00 = plane[y0 * WL + x0], v01 = plane[y0 * WL + x1];
  float v10 = plane[y1 * WL + x0], v11 = plane[y1 * WL + x1];
  out[idx] = (v00 * (1.f - wx) + v01 * wx) * (1.f - wy)
           + (v10 * (1.f - wx) + v11 * wx) * wy;
}

extern "C" void kernel_launch(void* const* d_in, const int* in_sizes, int n_in,
                              void* d_out, int out_size, void* d_ws, size_t ws_size,
                              hipStream_t stream) {
  const float* x_l     = (const float*)d_in[0];
  const float* x_h     = (const float*)d_in[1];
  const float* feat    = (const float*)d_in[2];
  const float* gn_l_w  = (const float*)d_in[3];
  const float* gn_l_b  = (const float*)d_in[4];
  const float* gn_h_w  = (const float*)d_in[5];
  const float* gn_h_b  = (const float*)d_in[6];
  const float* w_off   = (const float*)d_in[7];
  const float* s_off   = (const float*)d_in[8];
  const float* b_off   = (const float*)d_in[9];
  const float* w_off_h = (const float*)d_in[10];
  const float* s_off_h = (const float*)d_in[11];
  const float* b_off_h = (const float*)d_in[12];
  const float* w_ds    = (const float*)d_in[13];
  const float* s_ds    = (const float*)d_in[14];
  const float* b_ds    = (const float*)d_in[15];
  const float* w_ds_h  = (const float*)d_in[16];
  const float* s_ds_h  = (const float*)d_in[17];
  const float* b_ds_h  = (const float*)d_in[18];
  float* ws  = (float*)d_ws;
  float* out = (float*)d_out;

  k_stats1<<<1280, 256, 0, stream>>>(x_l, x_h, ws);
  k_stats2<<<32, 64, 0, stream>>>(gn_l_w, gn_l_b, gn_h_w, gn_h_b, ws);
  k_head<HL, WL, 64><<<(BATCH * HL * WL) / 64, 512, 0, stream>>>(
      x_l, w_off, w_ds, s_off, b_off, s_ds, b_ds,
      ws + WS_AL, ws + WS_BL, ws + WS_OFFL, ws + WS_DSL);
  k_head<HH, WH, 16><<<(BATCH * HH * WH) / 64, 512, 0, stream>>>(
      x_h, w_off_h, w_ds_h, s_off_h, b_off_h, s_ds_h, b_ds_h,
      ws + WS_AH, ws + WS_BH, ws + WS_OFFH, ws + WS_DSH);
  k_combine<<<(BATCH * 32 * HL * WL) / 256, 256, 0, stream>>>(ws);
  k_sample<<<(long)(BATCH * CFCH * HH * WH) / 256, 256, 0, stream>>>(feat, ws + WS_OFFS, out);
}

// Round 6
// 121.895 us; speedup vs baseline: 7.8070x; 1.2753x over previous
//
#include <hip/hip_runtime.h>
#include <math.h>

#define BATCH 2
#define CCH 64      // C
#define HL 128
#define WL 128
#define HH 256
#define WH 256
#define CFCH 256
#define CIN 72

// workspace layout (float offsets) — compact
constexpr long WS_AL   = 0;                     // a_l   (B*C = 128)
constexpr long WS_BL   = 128;                   // bb_l
constexpr long WS_AH   = 256;                   // a_h
constexpr long WS_BH   = 384;                   // bb_h
constexpr long WS_OFFL = 512;                   // 2*32*128*128 = 1048576
constexpr long WS_DSL  = WS_OFFL + 1048576;
constexpr long WS_OFFH = WS_DSL + 1048576;      // 2*8*256*256 = 1048576
constexpr long WS_DSH  = WS_OFFH + 1048576;
constexpr long WS_CRD  = WS_DSH + 1048576;      // float2[2*16*128*128] = 1048576 floats
constexpr long WS_PART = WS_CRD + 1048576;      // 32 groups * 64 slices * 2

// ---------------- K1a: partial sums over 8192-element slices ----------------
__global__ void k_stats1(const float* __restrict__ xl, const float* __restrict__ xh,
                         float* __restrict__ ws) {
  int blk = blockIdx.x;
  const float* x;
  long base;
  int gg, slice;
  if (blk < 256) {
    int g = blk >> 4; slice = blk & 15;
    x = xl; gg = g;
    base = (long)g * 8 * (HL * WL) + (long)slice * 8192;
  } else {
    int id = blk - 256;
    int g = id >> 6; slice = id & 63;
    x = xh; gg = 16 + g;
    base = (long)g * 8 * (HH * WH) + (long)slice * 8192;
  }
  const float4* p = (const float4*)(x + base);
  float s = 0.f, s2 = 0.f;
  #pragma unroll
  for (int k = 0; k < 8; k++) {
    float4 v = p[threadIdx.x + k * 256];
    s  += v.x + v.y + v.z + v.w;
    s2 += v.x * v.x + v.y * v.y + v.z * v.z + v.w * v.w;
  }
  __shared__ float sh1[256], sh2[256];
  sh1[threadIdx.x] = s; sh2[threadIdx.x] = s2;
  __syncthreads();
  for (int off = 128; off > 0; off >>= 1) {
    if (threadIdx.x < off) {
      sh1[threadIdx.x] += sh1[threadIdx.x + off];
      sh2[threadIdx.x] += sh2[threadIdx.x + off];
    }
    __syncthreads();
  }
  if (threadIdx.x == 0) {
    ws[WS_PART + (gg * 64 + slice) * 2]     = sh1[0];
    ws[WS_PART + (gg * 64 + slice) * 2 + 1] = sh2[0];
  }
}

// ---------------- K1b: finalize per-channel affine coefficients -------------
__global__ void k_stats2(const float* __restrict__ gwl, const float* __restrict__ gbl,
                         const float* __restrict__ gwh, const float* __restrict__ gbh,
                         float* __restrict__ ws) {
  int blk = blockIdx.x;          // 0..31
  bool high = blk >= 16;
  int id = blk & 15;
  int b = id >> 3, g = id & 7;
  int gg = high ? 16 + id : id;
  int nsl = high ? 64 : 16;
  long n = high ? (long)8 * HH * WH : (long)8 * HL * WL;
  float s = 0.f, s2 = 0.f;
  for (int i = threadIdx.x; i < nsl; i += 64) {
    s  += ws[WS_PART + (gg * 64 + i) * 2];
    s2 += ws[WS_PART + (gg * 64 + i) * 2 + 1];
  }
  for (int off = 32; off > 0; off >>= 1) {
    s  += __shfl_down(s, off);
    s2 += __shfl_down(s2, off);
  }
  __shared__ float shm[2];
  if (threadIdx.x == 0) { shm[0] = s; shm[1] = s2; }
  __syncthreads();
  if (threadIdx.x < 8) {
    float mean = shm[0] / (float)n;
    float var  = shm[1] / (float)n - mean * mean;
    float inv  = rsqrtf(var + 1e-5f);
    int c = g * 8 + threadIdx.x;
    const float* gw = high ? gwh : gwl;
    const float* gb = high ? gbh : gbl;
    float a  = gw[c] * inv;
    float bb = gb[c] - mean * a;
    float* abase = ws + (high ? WS_AH : WS_AL);
    abase[b * CCH + c] = a;
    abase[128 + b * CCH + c] = bb;
  }
}

// ---------------- K3/K4: fused sim + conv1x1_bn heads ----------------------
template<int HSZ, int WSZ, int NOUT>
__global__ __launch_bounds__(512) void k_head(
                       const float* __restrict__ x,
                       const float* __restrict__ w_off, const float* __restrict__ w_ds,
                       const float* __restrict__ s_off, const float* __restrict__ b_off,
                       const float* __restrict__ s_ds,  const float* __restrict__ b_ds,
                       const float* __restrict__ acoef, const float* __restrict__ bcoef,
                       float* __restrict__ out_off, float* __restrict__ out_ds) {
  constexpr int HW   = HSZ * WSZ;
  constexpr int half = NOUT / 2;
  constexpr int PER  = NOUT / 8;
  __shared__ float wsm[NOUT * CIN];
  __shared__ float xc[CCH * 64];
  __shared__ float psum[8 * 64];
  __shared__ float sims[8 * 64];
  __shared__ float asm_[CCH], bsm_[CCH];

  int tid = threadIdx.x;
  int px = tid & 63;
  int t  = tid >> 6;                 // wave index 0..7, wave-uniform
  int gpix = blockIdx.x * 64 + px;
  int xq = gpix % WSZ;
  int yq = (gpix / WSZ) % HSZ;
  int bq = gpix / (WSZ * HSZ);       // uniform per block

  for (int i = tid; i < NOUT * CIN; i += 512) {
    int o = i / CIN, c = i % CIN;
    wsm[i] = (o < half) ? w_off[o * CIN + c] : w_ds[(o - half) * CIN + c];
  }
  if (tid < CCH)            asm_[tid] = acoef[bq * CCH + tid];
  else if (tid < 2 * CCH)   bsm_[tid - CCH] = bcoef[bq * CCH + tid - CCH];
  __syncthreads();

  const float* ptr = x + ((long)(bq * CCH)) * HW + yq * WSZ + xq;

  // phase 0: center tile + sumsq partials
  {
    float ss = 0.f;
    #pragma unroll
    for (int k = 0; k < 8; k++) {
      int c = t * 8 + k;
      float v = fmaf(asm_[c], ptr[(long)c * HW], bsm_[c]);
      xc[c * 64 + px] = v;
      ss += v * v;
    }
    psum[t * 64 + px] = ss;
  }
  __syncthreads();

  // phase 1: neighbor t
  {
    const int dyv[8] = {-2,-2,-2, 0, 0, 2, 2, 2};
    const int dxv[8] = {-2, 0, 2,-2, 2,-2, 0, 2};
    int dy = dyv[t], dx = dxv[t];
    int yn = yq + dy;                // uniform
    int xn = xq + dx;                // per-lane
    bool ok = (yn >= 0 && yn < HSZ && xn >= 0 && xn < WSZ);
    float dot = 0.f, nbq = 0.f;
    if (ok) {
      const float* nptr = ptr + (long)dy * WSZ + dx;
      #pragma unroll 16
      for (int c = 0; c < CCH; c++) {
        float nb = fmaf(asm_[c], nptr[(long)c * HW], bsm_[c]);
        float xv = xc[c * 64 + px];
        dot += xv * nb;
        nbq += nb * nb;
      }
    }
    float cs = 0.f;
    #pragma unroll
    for (int tt = 0; tt < 8; tt++) cs += psum[tt * 64 + px];
    float cnc = sqrtf(cs);
    sims[t * 64 + px] = dot / fmaxf(cnc * sqrtf(nbq), 1e-8f);
  }
  __syncthreads();

  // phase 2: conv outputs for this wave
  {
    float sv[8];
    #pragma unroll
    for (int j = 0; j < 8; j++) sv[j] = sims[j * 64 + px];
    float acc[PER];
    #pragma unroll
    for (int ol = 0; ol < PER; ol++) acc[ol] = 0.f;
    int o0 = t * PER;
    #pragma unroll 4
    for (int c = 0; c < CCH; c += 4) {
      float x0v = xc[(c + 0) * 64 + px];
      float x1v = xc[(c + 1) * 64 + px];
      float x2v = xc[(c + 2) * 64 + px];
      float x3v = xc[(c + 3) * 64 + px];
      #pragma unroll
      for (int ol = 0; ol < PER; ol++) {
        const float4 w4 = *(const float4*)&wsm[(o0 + ol) * CIN + c];
        acc[ol] += w4.x * x0v + w4.y * x1v + w4.z * x2v + w4.w * x3v;
      }
    }
    #pragma unroll
    for (int ol = 0; ol < PER; ol++) {
      const float4 wa = *(const float4*)&wsm[(o0 + ol) * CIN + 64];
      const float4 wb = *(const float4*)&wsm[(o0 + ol) * CIN + 68];
      acc[ol] += wa.x * sv[0] + wa.y * sv[1] + wa.z * sv[2] + wa.w * sv[3]
               + wb.x * sv[4] + wb.y * sv[5] + wb.z * sv[6] + wb.w * sv[7];
    }
    #pragma unroll
    for (int ol = 0; ol < PER; ol++) {
      int o = o0 + ol;
      float v;
      float* dst;
      int oo;
      if (o < half) { v = acc[ol] * s_off[o] + b_off[o];             dst = out_off; oo = o; }
      else          { v = acc[ol] * s_ds[o - half] + b_ds[o - half]; dst = out_ds;  oo = o - half; }
      dst[((long)(bq * half + oo)) * HW + yq * WSZ + xq] = v;
    }
  }
}

// ---------------- K5: combine -> packed clipped sample coords --------------
// one thread per (b,sub,y,x); writes float2 (gx,gy) ready for bilinear.
__global__ __launch_bounds__(256) void k_combine(float* __restrict__ ws) {
  int idx = blockIdx.x * blockDim.x + threadIdx.x;   // B*16*128*128 = 524288
  int x = idx & 127;
  int y = (idx >> 7) & 127;
  int sub = (idx >> 14) & 15;
  int b = idx >> 18;
  int sdx = sub & 1, sdy = (sub >> 1) & 1;

  const float* offl = ws + WS_OFFL;
  const float* dsl  = ws + WS_DSL;
  const float* offh = ws + WS_OFFH;
  const float* dsh  = ws + WS_DSH;

  int lidx = idx + b * (16 * HL * WL);               // channel sub (of 32)
  float ol0 = offl[lidx],               dl0 = dsl[lidx];
  float ol1 = offl[lidx + 16 * HL * WL], dl1 = dsl[lidx + 16 * HL * WL];
  int Y = 2 * y + sdy, X = 2 * x + sdx;
  long h0 = ((long)(b * 8 + (sub >> 2)) * HH + Y) * WH + X;
  long h1 = h0 + (long)4 * HH * WH;
  float oh0 = offh[h0], dh0 = dsh[h0];
  float oh1 = offh[h1], dh1 = dsh[h1];
  float gate0 = 1.f / (1.f + expf(-(dl0 + dh0)));
  float gate1 = 1.f / (1.f + expf(-(dl1 + dh1)));
  float offx = (ol0 + oh0) * gate0 + (sdx ? 0.25f : -0.25f);
  float offy = (ol1 + oh1) * gate1 + (sdy ? 0.25f : -0.25f);
  float gx = fminf(fmaxf((float)x + offx, 0.f), (float)(WL - 1));
  float gy = fminf(fmaxf((float)y + offy, 0.f), (float)(HL - 1));
  float2* crd = (float2*)(ws + WS_CRD);
  crd[idx] = float2{gx, gy};
}

// ---------------- K6: bilinear sampler, 64 channels per thread -------------
__global__ __launch_bounds__(256) void k_sample(const float* __restrict__ feat,
                                                const float* __restrict__ ws,
                                                float* __restrict__ out) {
  // XCD-aware bijective swizzle: 2048 blocks, 8 XCDs, 256 blocks each ->
  // each XCD owns one contiguous (b,g) slab (64 feat planes = 4.2 MB, L2-fit).
  int bid = (blockIdx.x & 7) * 256 + (blockIdx.x >> 3);
  long idx = (long)bid * 256 + threadIdx.x;
  int X = idx & 255;
  int Y = (idx >> 8) & 255;
  int g = (idx >> 16) & 3;
  int b = (int)(idx >> 18);
  int x = X >> 1, sdx = X & 1, y = Y >> 1, sdy = Y & 1;
  int sub = 4 * g + 2 * sdy + sdx;

  const float2* crd = (const float2*)(ws + WS_CRD);
  int cidx = b * (16 * HL * WL) + sub * (HL * WL) + y * WL + x;
  float2 cc = crd[cidx];
  float gx = cc.x, gy = cc.y;

  float fx0 = floorf(gx), fy0 = floorf(gy);
  int x0 = (int)fx0, y0 = (int)fy0;
  float wx = gx - fx0, wy = gy - fy0;
  int x1 = min(x0 + 1, WL - 1), y1 = min(y0 + 1, HL - 1);
  int o00 = y0 * WL + x0, o01 = y0 * WL + x1;
  int o10 = y1 * WL + x0, o11 = y1 * WL + x1;
  float w00 = (1.f - wx) * (1.f - wy), w01 = wx * (1.f - wy);
  float w10 = (1.f - wx) * wy,         w11 = wx * wy;

  const float* plane = feat + ((long)(b * CFCH + g * 64)) * (HL * WL);
  float* optr = out + (((long)(b * CFCH + g * 64)) * HH + Y) * WH + X;
  #pragma unroll 8
  for (int cch = 0; cch < 64; cch++) {
    const float* p = plane + (long)cch * (HL * WL);
    float v = p[o00] * w00 + p[o01] * w01 + p[o10] * w10 + p[o11] * w11;
    optr[(long)cch * (HH * WH)] = v;
  }
}

extern "C" void kernel_launch(void* const* d_in, const int* in_sizes, int n_in,
                              void* d_out, int out_size, void* d_ws, size_t ws_size,
                              hipStream_t stream) {
  const float* x_l     = (const float*)d_in[0];
  const float* x_h     = (const float*)d_in[1];
  const float* feat    = (const float*)d_in[2];
  const float* gn_l_w  = (const float*)d_in[3];
  const float* gn_l_b  = (const float*)d_in[4];
  const float* gn_h_w  = (const float*)d_in[5];
  const float* gn_h_b  = (const float*)d_in[6];
  const float* w_off   = (const float*)d_in[7];
  const float* s_off   = (const float*)d_in[8];
  const float* b_off   = (const float*)d_in[9];
  const float* w_off_h = (const float*)d_in[10];
  const float* s_off_h = (const float*)d_in[11];
  const float* b_off_h = (const float*)d_in[12];
  const float* w_ds    = (const float*)d_in[13];
  const float* s_ds    = (const float*)d_in[14];
  const float* b_ds    = (const float*)d_in[15];
  const float* w_ds_h  = (const float*)d_in[16];
  const float* s_ds_h  = (const float*)d_in[17];
  const float* b_ds_h  = (const float*)d_in[18];
  float* ws  = (float*)d_ws;
  float* out = (float*)d_out;

  k_stats1<<<1280, 256, 0, stream>>>(x_l, x_h, ws);
  k_stats2<<<32, 64, 0, stream>>>(gn_l_w, gn_l_b, gn_h_w, gn_h_b, ws);
  k_head<HL, WL, 64><<<(BATCH * HL * WL) / 64, 512, 0, stream>>>(
      x_l, w_off, w_ds, s_off, b_off, s_ds, b_ds,
      ws + WS_AL, ws + WS_BL, ws + WS_OFFL, ws + WS_DSL);
  k_head<HH, WH, 16><<<(BATCH * HH * WH) / 64, 512, 0, stream>>>(
      x_h, w_off_h, w_ds_h, s_off_h, b_off_h, s_ds_h, b_ds_h,
      ws + WS_AH, ws + WS_BH, ws + WS_OFFH, ws + WS_DSH);
  k_combine<<<(BATCH * 16 * HL * WL) / 256, 256, 0, stream>>>(ws);
  k_sample<<<2048, 256, 0, stream>>>(feat, ws, out);
}

// Round 7
// 112.692 us; speedup vs baseline: 8.4446x; 1.0817x over previous
//
#include <hip/hip_runtime.h>
#include <math.h>

#define BATCH 2
#define CCH 64      // C
#define HL 128
#define WL 128
#define HH 256
#define WH 256
#define CFCH 256
#define CIN 72

// workspace layout (float offsets) — compact
constexpr long WS_AL   = 0;                     // a_l   (B*C = 128)
constexpr long WS_BL   = 128;                   // bb_l
constexpr long WS_AH   = 256;                   // a_h
constexpr long WS_BH   = 384;                   // bb_h
constexpr long WS_OFFL = 512;                   // 2*32*128*128 = 1048576
constexpr long WS_DSL  = WS_OFFL + 1048576;
constexpr long WS_OFFH = WS_DSL + 1048576;      // 2*8*256*256 = 1048576
constexpr long WS_DSH  = WS_OFFH + 1048576;
constexpr long WS_CRD  = WS_DSH + 1048576;      // float2[2*16*128*128] = 1048576 floats
constexpr long WS_PART = WS_CRD + 1048576;      // 32 groups * 64 slices * 2

// ---------------- K1a: partial sums over 8192-element slices ----------------
__global__ void k_stats1(const float* __restrict__ xl, const float* __restrict__ xh,
                         float* __restrict__ ws) {
  int blk = blockIdx.x;
  const float* x;
  long base;
  int gg, slice;
  if (blk < 256) {
    int g = blk >> 4; slice = blk & 15;
    x = xl; gg = g;
    base = (long)g * 8 * (HL * WL) + (long)slice * 8192;
  } else {
    int id = blk - 256;
    int g = id >> 6; slice = id & 63;
    x = xh; gg = 16 + g;
    base = (long)g * 8 * (HH * WH) + (long)slice * 8192;
  }
  const float4* p = (const float4*)(x + base);
  float s = 0.f, s2 = 0.f;
  #pragma unroll
  for (int k = 0; k < 8; k++) {
    float4 v = p[threadIdx.x + k * 256];
    s  += v.x + v.y + v.z + v.w;
    s2 += v.x * v.x + v.y * v.y + v.z * v.z + v.w * v.w;
  }
  __shared__ float sh1[256], sh2[256];
  sh1[threadIdx.x] = s; sh2[threadIdx.x] = s2;
  __syncthreads();
  for (int off = 128; off > 0; off >>= 1) {
    if (threadIdx.x < off) {
      sh1[threadIdx.x] += sh1[threadIdx.x + off];
      sh2[threadIdx.x] += sh2[threadIdx.x + off];
    }
    __syncthreads();
  }
  if (threadIdx.x == 0) {
    ws[WS_PART + (gg * 64 + slice) * 2]     = sh1[0];
    ws[WS_PART + (gg * 64 + slice) * 2 + 1] = sh2[0];
  }
}

// ---------------- K1b: finalize per-channel affine coefficients -------------
__global__ void k_stats2(const float* __restrict__ gwl, const float* __restrict__ gbl,
                         const float* __restrict__ gwh, const float* __restrict__ gbh,
                         float* __restrict__ ws) {
  int blk = blockIdx.x;          // 0..31
  bool high = blk >= 16;
  int id = blk & 15;
  int b = id >> 3, g = id & 7;
  int gg = high ? 16 + id : id;
  int nsl = high ? 64 : 16;
  long n = high ? (long)8 * HH * WH : (long)8 * HL * WL;
  float s = 0.f, s2 = 0.f;
  for (int i = threadIdx.x; i < nsl; i += 64) {
    s  += ws[WS_PART + (gg * 64 + i) * 2];
    s2 += ws[WS_PART + (gg * 64 + i) * 2 + 1];
  }
  for (int off = 32; off > 0; off >>= 1) {
    s  += __shfl_down(s, off);
    s2 += __shfl_down(s2, off);
  }
  __shared__ float shm[2];
  if (threadIdx.x == 0) { shm[0] = s; shm[1] = s2; }
  __syncthreads();
  if (threadIdx.x < 8) {
    float mean = shm[0] / (float)n;
    float var  = shm[1] / (float)n - mean * mean;
    float inv  = rsqrtf(var + 1e-5f);
    int c = g * 8 + threadIdx.x;
    const float* gw = high ? gwh : gwl;
    const float* gb = high ? gbh : gbl;
    float a  = gw[c] * inv;
    float bb = gb[c] - mean * a;
    float* abase = ws + (high ? WS_AH : WS_AL);
    abase[b * CCH + c] = a;
    abase[128 + b * CCH + c] = bb;
  }
}

// ---------------- K3/K4: fused sim + conv1x1_bn heads ----------------------
template<int HSZ, int WSZ, int NOUT>
__global__ __launch_bounds__(512) void k_head(
                       const float* __restrict__ x,
                       const float* __restrict__ w_off, const float* __restrict__ w_ds,
                       const float* __restrict__ s_off, const float* __restrict__ b_off,
                       const float* __restrict__ s_ds,  const float* __restrict__ b_ds,
                       const float* __restrict__ acoef, const float* __restrict__ bcoef,
                       float* __restrict__ out_off, float* __restrict__ out_ds) {
  constexpr int HW   = HSZ * WSZ;
  constexpr int half = NOUT / 2;
  constexpr int PER  = NOUT / 8;
  __shared__ float wsm[NOUT * CIN];
  __shared__ float xc[CCH * 64];
  __shared__ float psum[8 * 64];
  __shared__ float sims[8 * 64];
  __shared__ float asm_[CCH], bsm_[CCH];

  int tid = threadIdx.x;
  int px = tid & 63;
  int t  = tid >> 6;                 // wave index 0..7, wave-uniform
  int gpix = blockIdx.x * 64 + px;
  int xq = gpix % WSZ;
  int yq = (gpix / WSZ) % HSZ;
  int bq = gpix / (WSZ * HSZ);       // uniform per block

  for (int i = tid; i < NOUT * CIN; i += 512) {
    int o = i / CIN, c = i % CIN;
    wsm[i] = (o < half) ? w_off[o * CIN + c] : w_ds[(o - half) * CIN + c];
  }
  if (tid < CCH)            asm_[tid] = acoef[bq * CCH + tid];
  else if (tid < 2 * CCH)   bsm_[tid - CCH] = bcoef[bq * CCH + tid - CCH];
  __syncthreads();

  const float* ptr = x + ((long)(bq * CCH)) * HW + yq * WSZ + xq;

  // phase 0: center tile + sumsq partials
  {
    float ss = 0.f;
    #pragma unroll
    for (int k = 0; k < 8; k++) {
      int c = t * 8 + k;
      float v = fmaf(asm_[c], ptr[(long)c * HW], bsm_[c]);
      xc[c * 64 + px] = v;
      ss += v * v;
    }
    psum[t * 64 + px] = ss;
  }
  __syncthreads();

  // phase 1: neighbor t
  {
    const int dyv[8] = {-2,-2,-2, 0, 0, 2, 2, 2};
    const int dxv[8] = {-2, 0, 2,-2, 2,-2, 0, 2};
    int dy = dyv[t], dx = dxv[t];
    int yn = yq + dy;                // uniform
    int xn = xq + dx;                // per-lane
    bool ok = (yn >= 0 && yn < HSZ && xn >= 0 && xn < WSZ);
    float dot = 0.f, nbq = 0.f;
    if (ok) {
      const float* nptr = ptr + (long)dy * WSZ + dx;
      #pragma unroll 16
      for (int c = 0; c < CCH; c++) {
        float nb = fmaf(asm_[c], nptr[(long)c * HW], bsm_[c]);
        float xv = xc[c * 64 + px];
        dot += xv * nb;
        nbq += nb * nb;
      }
    }
    float cs = 0.f;
    #pragma unroll
    for (int tt = 0; tt < 8; tt++) cs += psum[tt * 64 + px];
    float cnc = sqrtf(cs);
    sims[t * 64 + px] = dot / fmaxf(cnc * sqrtf(nbq), 1e-8f);
  }
  __syncthreads();

  // phase 2: conv outputs for this wave
  {
    float sv[8];
    #pragma unroll
    for (int j = 0; j < 8; j++) sv[j] = sims[j * 64 + px];
    float acc[PER];
    #pragma unroll
    for (int ol = 0; ol < PER; ol++) acc[ol] = 0.f;
    int o0 = t * PER;
    #pragma unroll 4
    for (int c = 0; c < CCH; c += 4) {
      float x0v = xc[(c + 0) * 64 + px];
      float x1v = xc[(c + 1) * 64 + px];
      float x2v = xc[(c + 2) * 64 + px];
      float x3v = xc[(c + 3) * 64 + px];
      #pragma unroll
      for (int ol = 0; ol < PER; ol++) {
        const float4 w4 = *(const float4*)&wsm[(o0 + ol) * CIN + c];
        acc[ol] += w4.x * x0v + w4.y * x1v + w4.z * x2v + w4.w * x3v;
      }
    }
    #pragma unroll
    for (int ol = 0; ol < PER; ol++) {
      const float4 wa = *(const float4*)&wsm[(o0 + ol) * CIN + 64];
      const float4 wb = *(const float4*)&wsm[(o0 + ol) * CIN + 68];
      acc[ol] += wa.x * sv[0] + wa.y * sv[1] + wa.z * sv[2] + wa.w * sv[3]
               + wb.x * sv[4] + wb.y * sv[5] + wb.z * sv[6] + wb.w * sv[7];
    }
    #pragma unroll
    for (int ol = 0; ol < PER; ol++) {
      int o = o0 + ol;
      float v;
      float* dst;
      int oo;
      if (o < half) { v = acc[ol] * s_off[o] + b_off[o];             dst = out_off; oo = o; }
      else          { v = acc[ol] * s_ds[o - half] + b_ds[o - half]; dst = out_ds;  oo = o - half; }
      dst[((long)(bq * half + oo)) * HW + yq * WSZ + xq] = v;
    }
  }
}

// ---------------- K5: combine -> packed clipped sample coords --------------
// one thread per (b,sub,y,x); writes float2 (gx,gy) ready for bilinear.
__global__ __launch_bounds__(256) void k_combine(float* __restrict__ ws) {
  int idx = blockIdx.x * blockDim.x + threadIdx.x;   // B*16*128*128 = 524288
  int x = idx & 127;
  int y = (idx >> 7) & 127;
  int sub = (idx >> 14) & 15;
  int b = idx >> 18;
  int sdx = sub & 1, sdy = (sub >> 1) & 1;

  const float* offl = ws + WS_OFFL;
  const float* dsl  = ws + WS_DSL;
  const float* offh = ws + WS_OFFH;
  const float* dsh  = ws + WS_DSH;

  int lidx = idx + b * (16 * HL * WL);               // channel sub (of 32)
  float ol0 = offl[lidx],               dl0 = dsl[lidx];
  float ol1 = offl[lidx + 16 * HL * WL], dl1 = dsl[lidx + 16 * HL * WL];
  int Y = 2 * y + sdy, X = 2 * x + sdx;
  long h0 = ((long)(b * 8 + (sub >> 2)) * HH + Y) * WH + X;
  long h1 = h0 + (long)4 * HH * WH;
  float oh0 = offh[h0], dh0 = dsh[h0];
  float oh1 = offh[h1], dh1 = dsh[h1];
  float gate0 = 1.f / (1.f + expf(-(dl0 + dh0)));
  float gate1 = 1.f / (1.f + expf(-(dl1 + dh1)));
  float offx = (ol0 + oh0) * gate0 + (sdx ? 0.25f : -0.25f);
  float offy = (ol1 + oh1) * gate1 + (sdy ? 0.25f : -0.25f);
  float gx = fminf(fmaxf((float)x + offx, 0.f), (float)(WL - 1));
  float gy = fminf(fmaxf((float)y + offy, 0.f), (float)(HL - 1));
  float2* crd = (float2*)(ws + WS_CRD);
  crd[idx] = float2{gx, gy};
}

// ---------------- K6: bilinear sampler, 64 channels per thread -------------
// per-channel taps merged into two float2 row-loads; edge-adjusted so
// x1==x0+1 and y1==y0+1 always hold (x0+wx and y0+wy are invariant).
__global__ __launch_bounds__(256) void k_sample(const float* __restrict__ feat,
                                                const float* __restrict__ ws,
                                                float* __restrict__ out) {
  // XCD-aware bijective swizzle: 2048 blocks, 8 XCDs, 256 blocks each ->
  // each XCD owns one contiguous (b,g) slab (64 feat planes = 4.2 MB, L2-fit).
  int bid = (blockIdx.x & 7) * 256 + (blockIdx.x >> 3);
  long idx = (long)bid * 256 + threadIdx.x;
  int X = idx & 255;
  int Y = (idx >> 8) & 255;
  int g = (idx >> 16) & 3;
  int b = (int)(idx >> 18);
  int x = X >> 1, sdx = X & 1, y = Y >> 1, sdy = Y & 1;
  int sub = 4 * g + 2 * sdy + sdx;

  const float2* crd = (const float2*)(ws + WS_CRD);
  int cidx = b * (16 * HL * WL) + sub * (HL * WL) + y * WL + x;
  float2 cc = crd[cidx];
  float gx = cc.x, gy = cc.y;

  float fx0 = floorf(gx), fy0 = floorf(gy);
  int x0 = (int)fx0, y0 = (int)fy0;
  float wx = gx - fx0, wy = gy - fy0;
  // edge adjust: keeps x0+wx / y0+wy invariant, makes x1=x0+1, y1=y0+1 valid
  if (x0 >= WL - 1) { x0 = WL - 2; wx = 1.f; }
  if (y0 >= HL - 1) { y0 = HL - 2; wy = 1.f; }
  int o00 = y0 * WL + x0;
  float w00 = (1.f - wx) * (1.f - wy), w01 = wx * (1.f - wy);
  float w10 = (1.f - wx) * wy,         w11 = wx * wy;

  const float* plane = feat + ((long)(b * CFCH + g * 64)) * (HL * WL);
  float* optr = out + (((long)(b * CFCH + g * 64)) * HH + Y) * WH + X;
  #pragma unroll 16
  for (int cch = 0; cch < 64; cch++) {
    const float* p = plane + (long)cch * (HL * WL);
    float2 r0 = *(const float2*)(p + o00);
    float2 r1 = *(const float2*)(p + o00 + WL);
    float v = r0.x * w00 + r0.y * w01 + r1.x * w10 + r1.y * w11;
    optr[(long)cch * (HH * WH)] = v;
  }
}

extern "C" void kernel_launch(void* const* d_in, const int* in_sizes, int n_in,
                              void* d_out, int out_size, void* d_ws, size_t ws_size,
                              hipStream_t stream) {
  const float* x_l     = (const float*)d_in[0];
  const float* x_h     = (const float*)d_in[1];
  const float* feat    = (const float*)d_in[2];
  const float* gn_l_w  = (const float*)d_in[3];
  const float* gn_l_b  = (const float*)d_in[4];
  const float* gn_h_w  = (const float*)d_in[5];
  const float* gn_h_b  = (const float*)d_in[6];
  const float* w_off   = (const float*)d_in[7];
  const float* s_off   = (const float*)d_in[8];
  const float* b_off   = (const float*)d_in[9];
  const float* w_off_h = (const float*)d_in[10];
  const float* s_off_h = (const float*)d_in[11];
  const float* b_off_h = (const float*)d_in[12];
  const float* w_ds    = (const float*)d_in[13];
  const float* s_ds    = (const float*)d_in[14];
  const float* b_ds    = (const float*)d_in[15];
  const float* w_ds_h  = (const float*)d_in[16];
  const float* s_ds_h  = (const float*)d_in[17];
  const float* b_ds_h  = (const float*)d_in[18];
  float* ws  = (float*)d_ws;
  float* out = (float*)d_out;

  k_stats1<<<1280, 256, 0, stream>>>(x_l, x_h, ws);
  k_stats2<<<32, 64, 0, stream>>>(gn_l_w, gn_l_b, gn_h_w, gn_h_b, ws);
  k_head<HL, WL, 64><<<(BATCH * HL * WL) / 64, 512, 0, stream>>>(
      x_l, w_off, w_ds, s_off, b_off, s_ds, b_ds,
      ws + WS_AL, ws + WS_BL, ws + WS_OFFL, ws + WS_DSL);
  k_head<HH, WH, 16><<<(BATCH * HH * WH) / 64, 512, 0, stream>>>(
      x_h, w_off_h, w_ds_h, s_off_h, b_off_h, s_ds_h, b_ds_h,
      ws + WS_AH, ws + WS_BH, ws + WS_OFFH, ws + WS_DSH);
  k_combine<<<(BATCH * 16 * HL * WL) / 256, 256, 0, stream>>>(ws);
  k_sample<<<2048, 256, 0, stream>>>(feat, ws, out);
}